// Round 6
// baseline (555.083 us; speedup 1.0000x reference)
//
#include <hip/hip_runtime.h>

// ---------------------------------------------------------------------------
// Attention (Bahdanau): B=32, S=2048, H=512, 2H=1024, 4H=2048
//   u[b,h]      = bias[h] + dot(hidden[b,:1024], W[h,:1024])      (fp32, tiny)
//   scores[b,s] = sum_h v[h]*tanh(u[b,h] + dot(enc[b,s,:], W[h,1024:]))
//   attn        = softmax_s(scores);  context[b,d] = sum_s attn[b,s]*enc[b,s,d]
// R6: R5 + true double-buffering: A reg-prefetch 2 K-steps ahead, A/B LDS
// dbuf (51KB, 3 blocks/CU), ONE barrier per K-step, staging writes issued
// before compute so waitcnt drains overlap the MFMA phase.
// ---------------------------------------------------------------------------

typedef __fp16   half2v __attribute__((ext_vector_type(2)));   // pkrtz result type
typedef _Float16 half8  __attribute__((ext_vector_type(8)));   // MFMA operand type
typedef __attribute__((ext_vector_type(4)))  float f4;
typedef __attribute__((ext_vector_type(16))) float f16v;
typedef __attribute__((ext_vector_type(4)))  unsigned int uint4v;

__device__ __forceinline__ void gload_lds16(const void* g, void* l) {
    __builtin_amdgcn_global_load_lds(
        (const __attribute__((address_space(1))) unsigned int*)g,
        (__attribute__((address_space(3))) unsigned int*)l, 16, 0, 0);
}
__device__ __forceinline__ unsigned int bc2(half2v h) {
    return __builtin_bit_cast(unsigned int, h);
}

// ---------------------------------------------------------------------------
// Kernel 1: u[b,h] (blocks 0..63) + W2 f16 fragment-major pack (blocks 64..319)
// Pack: chunk g = kk*2048 + ntg*128 + kh*64 + l  holds 8 f16:
//   W[h = ntg*32 + (l&31)][1024 + kk*32 + kh*16 + (l>>5)*8 + j], j=0..7
// ---------------------------------------------------------------------------
__global__ __launch_bounds__(256) void prep_kernel(
    const float* __restrict__ hidden, const float* __restrict__ W,
    const float* __restrict__ bias, float* __restrict__ u,
    unsigned short* __restrict__ w2) {
    if (blockIdx.x < 64) {
        int t = blockIdx.x * 256 + threadIdx.x;   // 0..16383
        int b = t >> 9, h = t & 511;
        const f4* wr = (const f4*)(W + (size_t)h * 2048);
        const f4* hr = (const f4*)(hidden + (size_t)b * 1024);
        float acc = bias[h];
        #pragma unroll 4
        for (int i = 0; i < 256; ++i) {
            f4 w4 = wr[i]; f4 h4 = hr[i];
            acc += w4[0]*h4[0] + w4[1]*h4[1] + w4[2]*h4[2] + w4[3]*h4[3];
        }
        u[t] = acc;
    } else {
        int g = (blockIdx.x - 64) * 256 + threadIdx.x;   // 0..65535 chunks
        int kk = g >> 11, id = g & 2047;
        int ntg = id >> 7, kh = (id >> 6) & 1, l = id & 63;
        int h = (ntg << 5) + (l & 31);
        int kg = 1024 + (kk << 5) + (kh << 4) + ((l >> 5) << 3);
        const float* src = W + (size_t)h * 2048 + kg;
        f4 x0 = *(const f4*)src;
        f4 x1 = *(const f4*)(src + 4);
        half8 vh;
        #pragma unroll
        for (int j = 0; j < 4; ++j) vh[j] = (_Float16)x0[j];      // RN
        #pragma unroll
        for (int j = 0; j < 4; ++j) vh[4 + j] = (_Float16)x1[j];  // RN
        ((half8*)w2)[g] = vh;
    }
}

// ---------------------------------------------------------------------------
// Kernel 2: fused partial scores. Block = 64 s-rows x 256 h (one h-half),
// 256 threads (4 waves). Wave wl: n-quarter (64 h), all 64 rows (mt=2 of 32).
// grid 2048: sblk = blockIdx.x>>1 (enc tile shared by hh pair), hh = &1.
// LDS: A 2x8K + B 2x16K + u 1K + v 1K + partial 1K = 51KB -> 3 blocks/CU.
// ---------------------------------------------------------------------------
__global__ __launch_bounds__(256, 3) void score_kernel(
    const float* __restrict__ enc, const unsigned short* __restrict__ w2,
    const float* __restrict__ u, const float* __restrict__ v,
    float* __restrict__ scores_part) {
    __shared__ short Ahi[2][2048], Alo[2][2048]; // 64 rows x 32 k f16, chunk-major
    __shared__ short Bs[2][8192];                // 256 h  x 32 k f16, chunk-major
    __shared__ float u_s[256], v_s[256];
    __shared__ float partial[4][64];

    const int tid  = threadIdx.x;
    const int wl   = tid >> 6, lane = tid & 63;
    const int col  = lane & 31;              // MFMA 32x32 col / A row
    const int sblk = blockIdx.x >> 1, hh = blockIdx.x & 1;
    const int row0 = sblk * 64;
    const int b    = row0 >> 11;
    const float* encB = enc + (size_t)row0 * 1024;

    u_s[tid] = u[(b << 9) + (hh << 8) + tid];
    v_s[tid] = v[(hh << 8) + tid];

    f16v acc[2][2];
    #pragma unroll
    for (int mt = 0; mt < 2; ++mt)
        #pragma unroll
        for (int nt = 0; nt < 2; ++nt)
            #pragma unroll
            for (int r = 0; r < 16; ++r) acc[mt][nt][r] = 0.f;

    // A staging: thread t stages chunk t: mt=t>>7, kh=(t>>6)&1, l=t&63
    //   row = mt*32 + (l&31), kbase = kh*16 + (l>>5)*8
    const int s_mt = tid >> 7, s_kh = (tid >> 6) & 1, s_l = tid & 63;
    const int s_row = (s_mt << 5) + (s_l & 31);
    const int s_kb  = (s_kh << 4) + ((s_l >> 5) << 3);
    const float* aSrc = encB + (size_t)s_row * 1024 + s_kb;

    // --- helpers as lambdas ----------------------------------------------
    auto stageA = [&](int buf, const f4& x0, const f4& x1) {
        half2v h01 = __builtin_amdgcn_cvt_pkrtz(x0[0], x0[1]);
        half2v h23 = __builtin_amdgcn_cvt_pkrtz(x0[2], x0[3]);
        half2v h45 = __builtin_amdgcn_cvt_pkrtz(x1[0], x1[1]);
        half2v h67 = __builtin_amdgcn_cvt_pkrtz(x1[2], x1[3]);
        half2v l01 = __builtin_amdgcn_cvt_pkrtz(x0[0] - (float)h01[0], x0[1] - (float)h01[1]);
        half2v l23 = __builtin_amdgcn_cvt_pkrtz(x0[2] - (float)h23[0], x0[3] - (float)h23[1]);
        half2v l45 = __builtin_amdgcn_cvt_pkrtz(x1[0] - (float)h45[0], x1[1] - (float)h45[1]);
        half2v l67 = __builtin_amdgcn_cvt_pkrtz(x1[2] - (float)h67[0], x1[3] - (float)h67[1]);
        uint4v hp = {bc2(h01), bc2(h23), bc2(h45), bc2(h67)};
        uint4v lp = {bc2(l01), bc2(l23), bc2(l45), bc2(l67)};
        ((uint4v*)Ahi[buf])[tid] = hp;
        ((uint4v*)Alo[buf])[tid] = lp;
    };
    auto stageB = [&](int buf, int kk) {
        const char* bsrc = (const char*)w2 + (size_t)kk * 32768 + (hh << 14)
                           + (wl << 12) + lane * 16;
        char* bdst = (char*)Bs[buf] + (wl << 12);
        #pragma unroll
        for (int i = 0; i < 4; ++i)
            gload_lds16(bsrc + (i << 10), bdst + (i << 10));
    };

    // --- preamble: load A(0),A(1); stage A(0),B(0) ------------------------
    f4 pf0[2], pf1[2];
    pf0[0] = *(const f4*)(aSrc);           pf1[0] = *(const f4*)(aSrc + 4);
    pf0[1] = *(const f4*)(aSrc + 32);      pf1[1] = *(const f4*)(aSrc + 36);
    stageA(0, pf0[0], pf1[0]);
    stageB(0, 0);
    __syncthreads();

    #pragma unroll 2
    for (int kk = 0; kk < 32; ++kk) {
        const int cur = kk & 1, nxt = cur ^ 1;
        // 1. issue A(kk+2) global loads (consumed 1.8 iters later)
        const int k2 = (kk + 2 <= 31) ? kk + 2 : 31;
        f4 t0 = *(const f4*)(aSrc + (k2 << 5));
        f4 t1 = *(const f4*)(aSrc + (k2 << 5) + 4);
        // 2. stage A(kk+1) into LDS[nxt] (regs loaded 2 iters ago; ds_write
        //    drains during compute) + 3. issue B(kk+1) DMA into LDS[nxt]
        if (kk < 31) {
            stageA(nxt, pf0[nxt], pf1[nxt]);
            stageB(nxt, kk + 1);
        }
        // 4. compute from LDS[cur]: 2 kh x (2 mt x 2 nt x hi/lo) MFMAs
        const half8* Ah8 = (const half8*)Ahi[cur];
        const half8* Al8 = (const half8*)Alo[cur];
        const half8* Bh8 = (const half8*)Bs[cur];
        #pragma unroll
        for (int kh = 0; kh < 2; ++kh) {
            half8 ah0 = Ah8[(kh << 6) + lane];
            half8 ah1 = Ah8[128 + (kh << 6) + lane];
            half8 al0 = Al8[(kh << 6) + lane];
            half8 al1 = Al8[128 + (kh << 6) + lane];
            #pragma unroll
            for (int nt = 0; nt < 2; ++nt) {
                int ntl = (wl << 1) + nt;
                half8 b8 = Bh8[((ntl << 1) + kh) * 64 + lane];
                acc[0][nt] = __builtin_amdgcn_mfma_f32_32x32x16_f16(ah0, b8, acc[0][nt], 0, 0, 0);
                acc[0][nt] = __builtin_amdgcn_mfma_f32_32x32x16_f16(al0, b8, acc[0][nt], 0, 0, 0);
                acc[1][nt] = __builtin_amdgcn_mfma_f32_32x32x16_f16(ah1, b8, acc[1][nt], 0, 0, 0);
                acc[1][nt] = __builtin_amdgcn_mfma_f32_32x32x16_f16(al1, b8, acc[1][nt], 0, 0, 0);
            }
        }
        // 5. retire prefetched regs into the slot A(kk+2) belongs to
        pf0[cur] = t0; pf1[cur] = t1;
        // 6. single barrier: LDS[nxt] staging complete, LDS[cur] reads done
        __syncthreads();
    }
    // --- epilogue: tanh, v-weight, reduce over 256 h (block-local)
    // C/D layout 32x32: col = lane&31, row = (reg&3) + 8*(reg>>2) + 4*(lane>>5)
    const int rhalf = (lane >> 5) << 2;
    #pragma unroll
    for (int mt = 0; mt < 2; ++mt) {
        #pragma unroll
        for (int reg = 0; reg < 16; ++reg) {
            float ssum = 0.f;
            #pragma unroll
            for (int nt = 0; nt < 2; ++nt) {
                int hl = (((wl << 1) + nt) << 5) + col;
                float x = u_s[hl] + acc[mt][nt][reg];
                float t = __expf(2.f * x);               // tanh via exp
                float th = 1.f - 2.f / (t + 1.f);
                ssum += v_s[hl] * th;
            }
            ssum += __shfl_xor(ssum, 1);
            ssum += __shfl_xor(ssum, 2);
            ssum += __shfl_xor(ssum, 4);
            ssum += __shfl_xor(ssum, 8);
            ssum += __shfl_xor(ssum, 16);
            if (col == 0)
                partial[wl][(mt << 5) + (reg & 3) + ((reg >> 2) << 3) + rhalf] = ssum;
        }
    }
    __syncthreads();
    if (tid < 64) {
        float s = partial[0][tid] + partial[1][tid] + partial[2][tid] + partial[3][tid];
        scores_part[(hh << 16) + row0 + tid] = s;
    }
}

// ---------------------------------------------------------------------------
// Kernel 3: per-(b, 64-row s-chunk) softmax + partial context, 1024 blocks
// ---------------------------------------------------------------------------
__global__ __launch_bounds__(256) void ctx_partial_kernel(
    const float* __restrict__ enc, const float* __restrict__ scores_part,
    float* __restrict__ partials) {
    __shared__ float p_s[2048];
    __shared__ float wredm[4], wreds[4];
    const int t = threadIdx.x;
    const int b = blockIdx.x >> 5, sc = blockIdx.x & 31;
    const int wid = t >> 6, lane = t & 63;
    const float* s0 = scores_part + ((size_t)b << 11);
    const float* s1 = s0 + 65536;

    float vals[8];
    float mx = -1e30f;
    #pragma unroll
    for (int i = 0; i < 8; ++i) {
        int idx = t + (i << 8);
        vals[i] = s0[idx] + s1[idx];
        mx = fmaxf(mx, vals[i]);
    }
    #pragma unroll
    for (int off = 1; off < 64; off <<= 1) mx = fmaxf(mx, __shfl_xor(mx, off));
    if (lane == 0) wredm[wid] = mx;
    __syncthreads();
    mx = fmaxf(fmaxf(wredm[0], wredm[1]), fmaxf(wredm[2], wredm[3]));

    float lsum = 0.f;
    #pragma unroll
    for (int i = 0; i < 8; ++i) {
        float e = __expf(vals[i] - mx);
        p_s[t + (i << 8)] = e;
        lsum += e;
    }
    #pragma unroll
    for (int off = 1; off < 64; off <<= 1) lsum += __shfl_xor(lsum, off);
    if (lane == 0) wreds[wid] = lsum;
    __syncthreads();
    const float inv = 1.f / (wreds[0] + wreds[1] + wreds[2] + wreds[3]);

    f4 a = (f4){0.f, 0.f, 0.f, 0.f};
    const f4* erow = ((const f4*)(enc + ((size_t)b * 2048 + (sc << 6)) * 1024)) + t;
    #pragma unroll 4
    for (int i = 0; i < 64; ++i) {
        float p = p_s[(sc << 6) + i] * inv;
        f4 e = erow[(size_t)i << 8];
        a += p * e;
    }
    f4* dst = (f4*)(partials + (((size_t)(sc << 5) + b) << 10));
    dst[t] = a;
}

// ---------------------------------------------------------------------------
// Kernel 4: reduce 32 s-chunk partials -> context
// ---------------------------------------------------------------------------
__global__ __launch_bounds__(256) void ctx_reduce_kernel(
    const float* __restrict__ partials, float* __restrict__ out) {
    int i = blockIdx.x * 256 + threadIdx.x;   // 0..32767  (b*1024 + d)
    float s = 0.f;
    #pragma unroll
    for (int sc = 0; sc < 32; ++sc) s += partials[sc * 32768 + i];
    out[i] = s;
}

// ---------------------------------------------------------------------------
extern "C" void kernel_launch(void* const* d_in, const int* in_sizes, int n_in,
                              void* d_out, int out_size, void* d_ws, size_t ws_size,
                              hipStream_t stream) {
    const float* hidden = (const float*)d_in[0];   // [32,1024]
    const float* enc    = (const float*)d_in[1];   // [32,2048,1024]
    const float* W      = (const float*)d_in[2];   // [512,2048]
    const float* bias   = (const float*)d_in[3];   // [512]
    const float* v      = (const float*)d_in[4];   // [512]
    float* out = (float*)d_out;                    // [32,1024]
    char* ws = (char*)d_ws;

    // ws layout (bytes):
    float* u            = (float*)(ws);                    //    65536
    float* scores_part  = (float*)(ws + 65536);            //   524288 (2 halves)
    float* partials     = (float*)(ws + 589824);           //  4194304
    unsigned short* w2  = (unsigned short*)(ws + 4784128); //  1048576  (~5.8MB)

    prep_kernel<<<320, 256, 0, stream>>>(hidden, W, bias, u, w2);
    score_kernel<<<2048, 256, 0, stream>>>(enc, w2, u, v, scores_part);
    ctx_partial_kernel<<<1024, 256, 0, stream>>>(enc, scores_part, partials);
    ctx_reduce_kernel<<<128, 256, 0, stream>>>(partials, out);
}